// Round 10
// baseline (782.489 us; speedup 1.0000x reference)
//
#include <hip/hip_runtime.h>
#include <hip/hip_bf16.h>

using bf16 = __hip_bfloat16;
typedef __bf16 bf16x8_t __attribute__((ext_vector_type(8)));
typedef float f32x16_t __attribute__((ext_vector_type(16)));

#define BM 128
#define BN 128
#define BK 64

__device__ __forceinline__ void gload_lds16(const void* g, void* l) {
  __builtin_amdgcn_global_load_lds(
      (__attribute__((address_space(1))) void*)g,
      (__attribute__((address_space(3))) void*)l, 16, 0, 0);
}

// GELU via A&S 7.1.25 3-term erf (|err| < 2.5e-5; bf16 output => invisible)
__device__ __forceinline__ float gelu_erf(float t) {
  const float xs = fabsf(t) * 0.70710678118654752f;
  const float u = 1.0f / fmaf(0.47047f, xs, 1.0f);
  float p = fmaf(0.7478556f, u, -0.0958798f);
  p = fmaf(p, u, 0.3480242f);
  const float er = 1.0f - p * u * __expf(-xs * xs);
  const float ers = (t < 0.f) ? -er : er;
  return 0.5f * t * (1.0f + ers);
}

// ---------------- NT GEMM: C[m][n] = sum_k A[m][k] * B[n][k] ----------------
// m97 structure: 128x128 tile, BK=64, 4 waves, single-buffer LDS (32 KiB),
// 2 barriers/K-step, multi-block occupancy for overlap. Slot-XOR swizzle:
// LDS physical (row, slot) holds global (row, slot ^ (row&7)).
// MFMA = 32x32x16 (16 instrs/K-tile/wave, higher-ceiling pipe shape).
// Block order: XCD-bijective outer, GROUP_M=8 bm-fast super-tiles.
// EPI: 0 = bf16 out; 1 = bf16 out * scale; 2 = f32 out + resid;
//      3 = bf16 out gelu(acc+bias); 4 = f32 out += (in-place) acc + bias
template <int EPI>
__device__ __forceinline__ void gemm_body(
    const bf16* __restrict__ A, const bf16* __restrict__ B,
    void* __restrict__ Cv, int K, int lda, int ldb, int ldc,
    long long sA, long long sB, long long sC, float scale,
    const float* __restrict__ bias,
    const float* __restrict__ resid, long long sR, int ldr) {
  __shared__ __align__(16) bf16 As[BM * BK];
  __shared__ __align__(16) bf16 Bs[BN * BK];
  const int tid = threadIdx.x;
  const int lane = tid & 63, wid = tid >> 6;
  const int z = blockIdx.z;
  A += (size_t)z * sA;
  B += (size_t)z * sB;

  // T1: bijective XCD-aware block swizzle within the z-slice
  const int gx = gridDim.x, gy = gridDim.y;
  const int nwg = gx * gy;
  const int orig = blockIdx.x + gx * blockIdx.y;
  const int q = nwg >> 3, r = nwg & 7;
  const int xcd = orig & 7, loc = orig >> 3;
  const int wg = (xcd < r ? xcd * (q + 1) : r * (q + 1) + (xcd - r) * q) + loc;
  // GROUP_M=8 super-tile: bm-fast within 8-row groups (gy % 8 == 0 here)
  const int m_in = wg & 7;
  const int rest = wg >> 3;
  const int bn = (rest % gx) * BN;
  const int bm = ((rest / gx) * 8 + m_in) * BM;
  const int wr = wid >> 1, wc = wid & 1;

  // staging: 4 chunks/thread/operand; physical chunk ch = (row, slot),
  // global source slot = slot ^ (row&7); LDS dest linear.
  const bf16* ga[4];
  const bf16* gb[4];
  int lofs[4];
#pragma unroll
  for (int i = 0; i < 4; ++i) {
    int cb = i * 256 + wid * 64;  // wave-uniform chunk base
    int ch = cb + lane;
    int rr = ch >> 3, c = ch & 7;
    int cg = c ^ (rr & 7);        // pre-swizzled global slot
    ga[i] = A + (size_t)(bm + rr) * lda + cg * 8;
    gb[i] = B + (size_t)(bn + rr) * ldb + cg * 8;
    lofs[i] = cb * 8;
  }

  f32x16_t acc[2][2] = {};

  const int l31 = lane & 31, kg = lane >> 5;
  const int sw = l31 & 7;
  // phys slot for kstep ks: (ks*2 + kg) ^ sw  (elems = slot*8)
  int so[4];
#pragma unroll
  for (int ks = 0; ks < 4; ++ks) so[ks] = (((ks << 1) | kg) ^ sw) * 8;
  const int arow = wr * 64 + l31;
  const int brow = wc * 64 + l31;

  for (int kt = 0; kt < K; kt += BK) {
#pragma unroll
    for (int i = 0; i < 4; ++i) {
      gload_lds16(ga[i] + kt, As + lofs[i]);
      gload_lds16(gb[i] + kt, Bs + lofs[i]);
    }
    __syncthreads();
#pragma unroll
    for (int ks = 0; ks < 4; ++ks) {
      bf16x8_t av0, av1, bv0, bv1;
      av0 = *(const bf16x8_t*)(As + arow * BK + so[ks]);
      av1 = *(const bf16x8_t*)(As + (arow + 32) * BK + so[ks]);
      bv0 = *(const bf16x8_t*)(Bs + brow * BK + so[ks]);
      bv1 = *(const bf16x8_t*)(Bs + (brow + 32) * BK + so[ks]);
      acc[0][0] = __builtin_amdgcn_mfma_f32_32x32x16_bf16(av0, bv0, acc[0][0], 0, 0, 0);
      acc[0][1] = __builtin_amdgcn_mfma_f32_32x32x16_bf16(av0, bv1, acc[0][1], 0, 0, 0);
      acc[1][0] = __builtin_amdgcn_mfma_f32_32x32x16_bf16(av1, bv0, acc[1][0], 0, 0, 0);
      acc[1][1] = __builtin_amdgcn_mfma_f32_32x32x16_bf16(av1, bv1, acc[1][1], 0, 0, 0);
    }
    __syncthreads();
  }

  // epilogue (32x32 C/D: col=lane&31, row=(reg&3)+8*(reg>>2)+4*(lane>>5))
  const int row0 = bm + wr * 64 + 4 * kg;
  const int col0 = bn + wc * 64 + l31;
#pragma unroll
  for (int mf = 0; mf < 2; ++mf) {
#pragma unroll
    for (int nf = 0; nf < 2; ++nf) {
#pragma unroll
      for (int reg = 0; reg < 16; ++reg) {
        const int rr = row0 + mf * 32 + (reg & 3) + 8 * (reg >> 2);
        const int cc = col0 + nf * 32;
        const float v = acc[mf][nf][reg];
        if constexpr (EPI == 0) {
          ((bf16*)Cv)[(size_t)z * sC + (size_t)rr * ldc + cc] = __float2bfloat16(v);
        } else if constexpr (EPI == 1) {
          ((bf16*)Cv)[(size_t)z * sC + (size_t)rr * ldc + cc] =
              __float2bfloat16(v * scale);
        } else if constexpr (EPI == 2) {
          ((float*)Cv)[(size_t)z * sC + (size_t)rr * ldc + cc] =
              v + resid[(size_t)z * sR + (size_t)rr * ldr + cc];
        } else if constexpr (EPI == 3) {
          ((bf16*)Cv)[(size_t)z * sC + (size_t)rr * ldc + cc] =
              __float2bfloat16(gelu_erf(v + bias[cc]));
        } else {
          float* Cf = (float*)Cv + (size_t)z * sC;
          const size_t idx = (size_t)rr * ldc + cc;
          Cf[idx] = Cf[idx] + v + bias[cc];
        }
      }
    }
  }
}

// Named wrappers (rocprof attribution)
__global__ void gemm_qkv(const bf16* A, const bf16* B, void* C, int K, int lda,
                         int ldb, int ldc, long long sA, long long sB,
                         long long sC) {
  gemm_body<0>(A, B, C, K, lda, ldb, ldc, sA, sB, sC, 1.f, nullptr, nullptr, 0, 0);
}
__global__ void gemm_qkt(const bf16* A, const bf16* B, void* C, int K, int lda,
                         int ldb, int ldc, long long sA, long long sB,
                         long long sC, float scale) {
  gemm_body<1>(A, B, C, K, lda, ldb, ldc, sA, sB, sC, scale, nullptr, nullptr, 0, 0);
}
__global__ void gemm_pv(const bf16* A, const bf16* B, void* C, int K, int lda,
                        int ldb, int ldc, long long sA, long long sB,
                        long long sC, const float* resid, long long sR, int ldr) {
  gemm_body<2>(A, B, C, K, lda, ldb, ldc, sA, sB, sC, 1.f, nullptr, resid, sR, ldr);
}
__global__ void gemm_ffn1(const bf16* A, const bf16* B, void* C, int K, int lda,
                          int ldb, int ldc, const float* bias) {
  gemm_body<3>(A, B, C, K, lda, ldb, ldc, 0, 0, 0, 1.f, bias, nullptr, 0, 0);
}
__global__ void gemm_ffn2(const bf16* A, const bf16* B, void* C, int K, int lda,
                          int ldb, int ldc, const float* bias) {
  gemm_body<4>(A, B, C, K, lda, ldb, ldc, 0, 0, 0, 1.f, bias, nullptr, 0, 0);
}

// ---------------- LayerNorm: fp32 in -> bf16 out, row length 1024 ----------
__global__ void ln_kernel(const float* __restrict__ X, const float* __restrict__ gw,
                          const float* __restrict__ bw, bf16* __restrict__ Y) {
  const int row = blockIdx.x, tid = threadIdx.x;
  const float4 xv = *(const float4*)(X + (size_t)row * 1024 + tid * 4);
  float s = xv.x + xv.y + xv.z + xv.w;
  float ss = xv.x * xv.x + xv.y * xv.y + xv.z * xv.z + xv.w * xv.w;
  __shared__ float red[8];
#pragma unroll
  for (int o = 32; o; o >>= 1) {
    s += __shfl_xor(s, o);
    ss += __shfl_xor(ss, o);
  }
  if ((tid & 63) == 0) {
    red[tid >> 6] = s;
    red[4 + (tid >> 6)] = ss;
  }
  __syncthreads();
  s = red[0] + red[1] + red[2] + red[3];
  ss = red[4] + red[5] + red[6] + red[7];
  const float mu = s * (1.f / 1024.f);
  const float var = ss * (1.f / 1024.f) - mu * mu;
  const float rs = rsqrtf(var + 1e-5f);
  const float4 gv = *(const float4*)(gw + tid * 4);
  const float4 bv = *(const float4*)(bw + tid * 4);
  union { ushort4 u; bf16 h[4]; } p;
  p.h[0] = __float2bfloat16((xv.x - mu) * rs * gv.x + bv.x);
  p.h[1] = __float2bfloat16((xv.y - mu) * rs * gv.y + bv.y);
  p.h[2] = __float2bfloat16((xv.z - mu) * rs * gv.z + bv.z);
  p.h[3] = __float2bfloat16((xv.w - mu) * rs * gv.w + bv.w);
  *(ushort4*)(Y + (size_t)row * 1024 + tid * 4) = p.u;
}

// ---------------- Softmax over rows of 2048 bf16 -> bf16 -------------------
__global__ void softmax_kernel(const bf16* __restrict__ S, bf16* __restrict__ P) {
  const size_t row = blockIdx.x;
  const int tid = threadIdx.x;
  union { uint4 u; unsigned short s[8]; } in;
  in.u = *(const uint4*)(S + row * 2048 + tid * 8);
  float f[8];
#pragma unroll
  for (int j = 0; j < 8; ++j)
    f[j] = __uint_as_float((unsigned)in.s[j] << 16);
  float m = f[0];
#pragma unroll
  for (int j = 1; j < 8; ++j) m = fmaxf(m, f[j]);
  __shared__ float red[4];
#pragma unroll
  for (int o = 32; o; o >>= 1) m = fmaxf(m, __shfl_xor(m, o));
  if ((tid & 63) == 0) red[tid >> 6] = m;
  __syncthreads();
  m = fmaxf(fmaxf(red[0], red[1]), fmaxf(red[2], red[3]));
  float s = 0.f;
#pragma unroll
  for (int j = 0; j < 8; ++j) {
    f[j] = __expf(f[j] - m);
    s += f[j];
  }
#pragma unroll
  for (int o = 32; o; o >>= 1) s += __shfl_xor(s, o);
  __syncthreads();
  if ((tid & 63) == 0) red[tid >> 6] = s;
  __syncthreads();
  s = red[0] + red[1] + red[2] + red[3];
  const float inv = 1.f / s;
  union { uint4 u; bf16 h[8]; } p;
#pragma unroll
  for (int j = 0; j < 8; ++j) p.h[j] = __float2bfloat16(f[j] * inv);
  *(uint4*)(P + row * 2048 + tid * 8) = p.u;
}

// ------- Transpose + convert fp32 W[K][N] -> bf16 WT[rowoff+n][k] ----------
__global__ void transpose_conv(const float* __restrict__ W, bf16* __restrict__ WT,
                               int Nd, int ldT, int rowoff) {
  __shared__ float t[32][33];
  const int tx = threadIdx.x, ty = threadIdx.y;
  const int n0 = blockIdx.x * 32, k0 = blockIdx.y * 32;
#pragma unroll
  for (int j = 0; j < 4; ++j)
    t[ty + 8 * j][tx] = W[(size_t)(k0 + ty + 8 * j) * Nd + n0 + tx];
  __syncthreads();
#pragma unroll
  for (int j = 0; j < 4; ++j)
    WT[(size_t)(rowoff + n0 + ty + 8 * j) * ldT + k0 + tx] =
        __float2bfloat16(t[tx][ty + 8 * j]);
}

// ------- bf16 transpose: dst[c][r] = src[r][c], batched over z -------------
__global__ void transpose_bf16(const bf16* __restrict__ src, bf16* __restrict__ dst,
                               int ldsrc, int lddst, long long zs, long long zd) {
  __shared__ bf16 t[32][33];
  const int z = blockIdx.z;
  src += (size_t)z * zs;
  dst += (size_t)z * zd;
  const int tx = threadIdx.x, ty = threadIdx.y;
  const int c0 = blockIdx.x * 32, r0 = blockIdx.y * 32;
#pragma unroll
  for (int j = 0; j < 4; ++j)
    t[ty + 8 * j][tx] = src[(size_t)(r0 + ty + 8 * j) * ldsrc + c0 + tx];
  __syncthreads();
#pragma unroll
  for (int j = 0; j < 4; ++j)
    dst[(size_t)(c0 + ty + 8 * j) * lddst + r0 + tx] = t[tx][ty + 8 * j];
}

extern "C" void kernel_launch(void* const* d_in, const int* in_sizes, int n_in,
                              void* d_out, int out_size, void* d_ws, size_t ws_size,
                              hipStream_t stream) {
  const float* x = (const float*)d_in[0];
  const float* ln1_g = (const float*)d_in[1];
  const float* ln1_b = (const float*)d_in[2];
  const float* Wq = (const float*)d_in[3];
  const float* Wk = (const float*)d_in[4];
  const float* Wv = (const float*)d_in[5];
  const float* ln2_g = (const float*)d_in[6];
  const float* ln2_b = (const float*)d_in[7];
  const float* W1 = (const float*)d_in[8];
  const float* b1 = (const float*)d_in[9];
  const float* W2 = (const float*)d_in[10];
  const float* b2 = (const float*)d_in[11];
  float* out = (float*)d_out;

  constexpr int B = 8, N = 2048, H = 1024, F = 4096;
  constexpr int M = B * N;  // 16384

  const size_t WqkvTB = (size_t)3 * H * H * 2;
  const size_t W1TB = (size_t)H * F * 2;
  const size_t W2TB = (size_t)H * F * 2;
  const size_t yB = (size_t)M * H * 2;
  const size_t vTB = (size_t)M * H * 2;
  const size_t qkvB = (size_t)M * 3 * H * 2;
  const size_t SB1 = (size_t)N * N * 2;   // bf16 scores
  const size_t attB1 = (size_t)N * N * 2;
  const size_t hB = (size_t)M * F * 2;
  const size_t fixedB = WqkvTB + W1TB + W2TB + yB + vTB;

  int g = 8;
  for (; g > 1; g >>= 1) {
    size_t R = qkvB + (size_t)g * (SB1 + attB1);
    if (R < hB) R = hB;
    if (fixedB + R <= ws_size) break;
  }

  char* ws = (char*)d_ws;
  size_t o = 0;
  bf16* wqkvT = (bf16*)(ws + o); o += WqkvTB;
  bf16* w1T = (bf16*)(ws + o);   o += W1TB;
  bf16* w2T = (bf16*)(ws + o);   o += W2TB;
  bf16* y = (bf16*)(ws + o);     o += yB;
  bf16* vT = (bf16*)(ws + o);    o += vTB;
  char* Rb = ws + o;
  bf16* qkv = (bf16*)Rb;
  bf16* S = (bf16*)(Rb + qkvB);
  bf16* att = (bf16*)(Rb + qkvB + (size_t)g * SB1);
  bf16* h = (bf16*)Rb;  // overlays qkv/S/att after attention is done

  const dim3 tb(32, 8);
  transpose_conv<<<dim3(H / 32, H / 32), tb, 0, stream>>>(Wq, wqkvT, H, H, 0);
  transpose_conv<<<dim3(H / 32, H / 32), tb, 0, stream>>>(Wk, wqkvT, H, H, H);
  transpose_conv<<<dim3(H / 32, H / 32), tb, 0, stream>>>(Wv, wqkvT, H, H, 2 * H);
  transpose_conv<<<dim3(F / 32, H / 32), tb, 0, stream>>>(W1, w1T, F, H, 0);
  transpose_conv<<<dim3(H / 32, F / 32), tb, 0, stream>>>(W2, w2T, H, F, 0);

  ln_kernel<<<M, 256, 0, stream>>>(x, ln1_g, ln1_b, y);

  gemm_qkv<<<dim3(3 * H / BN, M / BM, 1), 256, 0, stream>>>(
      y, wqkvT, qkv, H, H, H, 3 * H, 0, 0, 0);

  transpose_bf16<<<dim3(H / 32, N / 32, B), tb, 0, stream>>>(
      qkv + 2 * H, vT, 3 * H, N, (long long)N * 3 * H, (long long)H * N);

  for (int b0 = 0; b0 < B; b0 += g) {
    const bf16* qb = qkv + (size_t)b0 * N * 3 * H;
    gemm_qkt<<<dim3(N / BN, N / BM, g), 256, 0, stream>>>(
        qb, qb + H, S, H, 3 * H, 3 * H, N, (long long)N * 3 * H,
        (long long)N * 3 * H, (long long)N * N, 0.03125f);
    softmax_kernel<<<g * N, 256, 0, stream>>>(S, att);
    gemm_pv<<<dim3(H / BN, N / BM, g), 256, 0, stream>>>(
        att, vT + (size_t)b0 * H * N, out + (size_t)b0 * N * H, N, N, N, H,
        (long long)N * N, (long long)H * N, (long long)N * H,
        x + (size_t)b0 * N * H, (long long)N * H, H);
  }

  ln_kernel<<<M, 256, 0, stream>>>(out, ln2_g, ln2_b, y);

  gemm_ffn1<<<dim3(F / BN, M / BM, 1), 256, 0, stream>>>(
      y, w1T, h, H, H, H, F, b1);

  gemm_ffn2<<<dim3(H / BN, M / BM, 1), 256, 0, stream>>>(
      h, w2T, out, F, F, F, H, b2);
}

// Round 11
// 706.415 us; speedup vs baseline: 1.1077x; 1.1077x over previous
//
#include <hip/hip_runtime.h>
#include <hip/hip_bf16.h>

using bf16 = __hip_bfloat16;
typedef __bf16 bf16x8_t __attribute__((ext_vector_type(8)));
typedef float f32x4_t __attribute__((ext_vector_type(4)));

#define BM 128
#define BN 128
#define BK 64

__device__ __forceinline__ void gload_lds16(const void* g, void* l) {
  __builtin_amdgcn_global_load_lds(
      (__attribute__((address_space(1))) void*)g,
      (__attribute__((address_space(3))) void*)l, 16, 0, 0);
}

// GELU via A&S 7.1.25 3-term erf (|err| < 2.5e-5; bf16 output => invisible)
__device__ __forceinline__ float gelu_erf(float t) {
  const float xs = fabsf(t) * 0.70710678118654752f;
  const float u = 1.0f / fmaf(0.47047f, xs, 1.0f);
  float p = fmaf(0.7478556f, u, -0.0958798f);
  p = fmaf(p, u, 0.3480242f);
  const float er = 1.0f - p * u * __expf(-xs * xs);
  const float ers = (t < 0.f) ? -er : er;
  return 0.5f * t * (1.0f + ers);
}

// ---------------- NT GEMM: C[m][n] = sum_k A[m][k] * B[n][k] ----------------
// m97 structure (verified best here): 128x128 tile, BK=64, 4 waves,
// single-buffer LDS (32 KiB), 2 barriers/K-step, multi-block occupancy.
// Slot-XOR swizzle: LDS physical (row, slot) holds global (row, slot^(row&7))
// -> 0 measured bank conflicts with the 16x16 fragment read pattern.
// Block order: XCD-bijective outer, GROUP_M=8 bm-fast super-tiles.
// EPI: 0 = bf16 out; 1 = bf16 out * scale; 2 = f32 out + resid;
//      3 = bf16 out gelu(acc+bias); 4 = f32 out += (in-place) acc + bias
template <int EPI>
__device__ __forceinline__ void gemm_body(
    const bf16* __restrict__ A, const bf16* __restrict__ B,
    void* __restrict__ Cv, int K, int lda, int ldb, int ldc,
    long long sA, long long sB, long long sC, float scale,
    const float* __restrict__ bias,
    const float* __restrict__ resid, long long sR, int ldr) {
  __shared__ __align__(16) bf16 As[BM * BK];
  __shared__ __align__(16) bf16 Bs[BN * BK];
  const int tid = threadIdx.x;
  const int lane = tid & 63, wid = tid >> 6;
  const int z = blockIdx.z;
  A += (size_t)z * sA;
  B += (size_t)z * sB;

  // T1: bijective XCD-aware block swizzle within the z-slice
  const int gx = gridDim.x, gy = gridDim.y;
  const int nwg = gx * gy;
  const int orig = blockIdx.x + gx * blockIdx.y;
  const int q = nwg >> 3, r = nwg & 7;
  const int xcd = orig & 7, loc = orig >> 3;
  const int wg = (xcd < r ? xcd * (q + 1) : r * (q + 1) + (xcd - r) * q) + loc;
  // GROUP_M=8 super-tile: bm-fast within 8-row groups (gy % 8 == 0 here)
  const int m_in = wg & 7;
  const int rest = wg >> 3;
  const int bn = (rest % gx) * BN;
  const int bm = ((rest / gx) * 8 + m_in) * BM;
  const int wr = wid >> 1, wc = wid & 1;

  // staging: 4 chunks/thread/operand; physical chunk ch = (row, slot),
  // global source slot = slot ^ (row&7); LDS dest linear.
  const bf16* ga[4];
  const bf16* gb[4];
  int lofs[4];
#pragma unroll
  for (int i = 0; i < 4; ++i) {
    int cb = i * 256 + wid * 64;  // wave-uniform chunk base
    int ch = cb + lane;
    int rr = ch >> 3, c = ch & 7;
    int cg = c ^ (rr & 7);        // pre-swizzled global slot
    ga[i] = A + (size_t)(bm + rr) * lda + cg * 8;
    gb[i] = B + (size_t)(bn + rr) * ldb + cg * 8;
    lofs[i] = cb * 8;
  }

  f32x4_t acc[4][4];
#pragma unroll
  for (int i = 0; i < 4; ++i)
#pragma unroll
    for (int j = 0; j < 4; ++j) acc[i][j] = (f32x4_t){0.f, 0.f, 0.f, 0.f};

  const int l15 = lane & 15, kg = lane >> 4;
  const int sw = l15 & 7;                 // (row&7) for every row this lane reads
  const int s0 = (kg ^ sw) * 8;           // kk=0 physical slot offset (elems)
  const int s1 = ((4 + kg) ^ sw) * 8;     // kk=1
  const int arow = wr * 64 + l15;
  const int brow = wc * 64 + l15;

  for (int kt = 0; kt < K; kt += BK) {
#pragma unroll
    for (int i = 0; i < 4; ++i) {
      gload_lds16(ga[i] + kt, As + lofs[i]);
      gload_lds16(gb[i] + kt, Bs + lofs[i]);
    }
    __syncthreads();
#pragma unroll
    for (int kk = 0; kk < 2; ++kk) {
      const int so = kk ? s1 : s0;
      bf16x8_t av[4], bv[4];
#pragma unroll
      for (int i = 0; i < 4; ++i)
        av[i] = *(const bf16x8_t*)(As + (arow + i * 16) * BK + so);
#pragma unroll
      for (int j = 0; j < 4; ++j)
        bv[j] = *(const bf16x8_t*)(Bs + (brow + j * 16) * BK + so);
#pragma unroll
      for (int i = 0; i < 4; ++i)
#pragma unroll
        for (int j = 0; j < 4; ++j)
          acc[i][j] = __builtin_amdgcn_mfma_f32_16x16x32_bf16(av[i], bv[j],
                                                              acc[i][j], 0, 0, 0);
    }
    __syncthreads();
  }

  // epilogue (16x16 C/D: col=lane&15, row=(lane>>4)*4+reg)
  const int row0 = bm + wr * 64 + kg * 4;
  const int col0 = bn + wc * 64 + l15;
#pragma unroll
  for (int i = 0; i < 4; ++i) {
#pragma unroll
    for (int j = 0; j < 4; ++j) {
#pragma unroll
      for (int jj = 0; jj < 4; ++jj) {
        const int rr = row0 + i * 16 + jj;
        const int cc = col0 + j * 16;
        const float v = acc[i][j][jj];
        if constexpr (EPI == 0) {
          ((bf16*)Cv)[(size_t)z * sC + (size_t)rr * ldc + cc] = __float2bfloat16(v);
        } else if constexpr (EPI == 1) {
          ((bf16*)Cv)[(size_t)z * sC + (size_t)rr * ldc + cc] =
              __float2bfloat16(v * scale);
        } else if constexpr (EPI == 2) {
          ((float*)Cv)[(size_t)z * sC + (size_t)rr * ldc + cc] =
              v + resid[(size_t)z * sR + (size_t)rr * ldr + cc];
        } else if constexpr (EPI == 3) {
          ((bf16*)Cv)[(size_t)z * sC + (size_t)rr * ldc + cc] =
              __float2bfloat16(gelu_erf(v + bias[cc]));
        } else {
          float* Cf = (float*)Cv + (size_t)z * sC;
          const size_t idx = (size_t)rr * ldc + cc;
          Cf[idx] = Cf[idx] + v + bias[cc];
        }
      }
    }
  }
}

// Named wrappers (rocprof attribution)
__global__ void gemm_qkv(const bf16* A, const bf16* B, void* C, int K, int lda,
                         int ldb, int ldc, long long sA, long long sB,
                         long long sC) {
  gemm_body<0>(A, B, C, K, lda, ldb, ldc, sA, sB, sC, 1.f, nullptr, nullptr, 0, 0);
}
__global__ void gemm_qkt(const bf16* A, const bf16* B, void* C, int K, int lda,
                         int ldb, int ldc, long long sA, long long sB,
                         long long sC, float scale) {
  gemm_body<1>(A, B, C, K, lda, ldb, ldc, sA, sB, sC, scale, nullptr, nullptr, 0, 0);
}
__global__ void gemm_pv(const bf16* A, const bf16* B, void* C, int K, int lda,
                        int ldb, int ldc, long long sA, long long sB,
                        long long sC, const float* resid, long long sR, int ldr) {
  gemm_body<2>(A, B, C, K, lda, ldb, ldc, sA, sB, sC, 1.f, nullptr, resid, sR, ldr);
}
__global__ void gemm_ffn1(const bf16* A, const bf16* B, void* C, int K, int lda,
                          int ldb, int ldc, const float* bias) {
  gemm_body<3>(A, B, C, K, lda, ldb, ldc, 0, 0, 0, 1.f, bias, nullptr, 0, 0);
}
__global__ void gemm_ffn2(const bf16* A, const bf16* B, void* C, int K, int lda,
                          int ldb, int ldc, const float* bias) {
  gemm_body<4>(A, B, C, K, lda, ldb, ldc, 0, 0, 0, 1.f, bias, nullptr, 0, 0);
}

// ---------------- LayerNorm: fp32 in -> bf16 out, row length 1024 ----------
__global__ void ln_kernel(const float* __restrict__ X, const float* __restrict__ gw,
                          const float* __restrict__ bw, bf16* __restrict__ Y) {
  const int row = blockIdx.x, tid = threadIdx.x;
  const float4 xv = *(const float4*)(X + (size_t)row * 1024 + tid * 4);
  float s = xv.x + xv.y + xv.z + xv.w;
  float ss = xv.x * xv.x + xv.y * xv.y + xv.z * xv.z + xv.w * xv.w;
  __shared__ float red[8];
#pragma unroll
  for (int o = 32; o; o >>= 1) {
    s += __shfl_xor(s, o);
    ss += __shfl_xor(ss, o);
  }
  if ((tid & 63) == 0) {
    red[tid >> 6] = s;
    red[4 + (tid >> 6)] = ss;
  }
  __syncthreads();
  s = red[0] + red[1] + red[2] + red[3];
  ss = red[4] + red[5] + red[6] + red[7];
  const float mu = s * (1.f / 1024.f);
  const float var = ss * (1.f / 1024.f) - mu * mu;
  const float rs = rsqrtf(var + 1e-5f);
  const float4 gv = *(const float4*)(gw + tid * 4);
  const float4 bv = *(const float4*)(bw + tid * 4);
  union { ushort4 u; bf16 h[4]; } p;
  p.h[0] = __float2bfloat16((xv.x - mu) * rs * gv.x + bv.x);
  p.h[1] = __float2bfloat16((xv.y - mu) * rs * gv.y + bv.y);
  p.h[2] = __float2bfloat16((xv.z - mu) * rs * gv.z + bv.z);
  p.h[3] = __float2bfloat16((xv.w - mu) * rs * gv.w + bv.w);
  *(ushort4*)(Y + (size_t)row * 1024 + tid * 4) = p.u;
}

// ---------------- Softmax over rows of 2048 bf16 -> bf16 -------------------
__global__ void softmax_kernel(const bf16* __restrict__ S, bf16* __restrict__ P) {
  const size_t row = blockIdx.x;
  const int tid = threadIdx.x;
  union { uint4 u; unsigned short s[8]; } in;
  in.u = *(const uint4*)(S + row * 2048 + tid * 8);
  float f[8];
#pragma unroll
  for (int j = 0; j < 8; ++j)
    f[j] = __uint_as_float((unsigned)in.s[j] << 16);
  float m = f[0];
#pragma unroll
  for (int j = 1; j < 8; ++j) m = fmaxf(m, f[j]);
  __shared__ float red[4];
#pragma unroll
  for (int o = 32; o; o >>= 1) m = fmaxf(m, __shfl_xor(m, o));
  if ((tid & 63) == 0) red[tid >> 6] = m;
  __syncthreads();
  m = fmaxf(fmaxf(red[0], red[1]), fmaxf(red[2], red[3]));
  float s = 0.f;
#pragma unroll
  for (int j = 0; j < 8; ++j) {
    f[j] = __expf(f[j] - m);
    s += f[j];
  }
#pragma unroll
  for (int o = 32; o; o >>= 1) s += __shfl_xor(s, o);
  __syncthreads();
  if ((tid & 63) == 0) red[tid >> 6] = s;
  __syncthreads();
  s = red[0] + red[1] + red[2] + red[3];
  const float inv = 1.f / s;
  union { uint4 u; bf16 h[8]; } p;
#pragma unroll
  for (int j = 0; j < 8; ++j) p.h[j] = __float2bfloat16(f[j] * inv);
  *(uint4*)(P + row * 2048 + tid * 8) = p.u;
}

// ---- Batched transpose+convert of all 5 weights (one launch) --------------
// Tile t covers: [0,3072)   Wq/Wk/Wv (1024 tiles each, 32x32 grid, H x H)
//                [3072,7168) W1 (n over F: 128 x, k over H: 32 y)
//                [7168,11264) W2 (n over H: 32 x, k over F: 128 y)
__global__ void transpose_conv_all(const float* __restrict__ Wq,
                                   const float* __restrict__ Wk,
                                   const float* __restrict__ Wv,
                                   const float* __restrict__ W1,
                                   const float* __restrict__ W2,
                                   bf16* __restrict__ wqkvT,
                                   bf16* __restrict__ w1T,
                                   bf16* __restrict__ w2T) {
  __shared__ float t[32][33];
  const int tile = blockIdx.x;
  const float* W;
  bf16* WT;
  int Nd, ldT, rowoff, n0, k0;
  if (tile < 3072) {
    const int w = tile >> 10, rr = tile & 1023;
    W = (w == 0) ? Wq : (w == 1) ? Wk : Wv;
    WT = wqkvT; Nd = 1024; ldT = 1024; rowoff = w * 1024;
    n0 = (rr & 31) * 32; k0 = (rr >> 5) * 32;
  } else if (tile < 7168) {
    const int rr = tile - 3072;
    W = W1; WT = w1T; Nd = 4096; ldT = 1024; rowoff = 0;
    n0 = (rr & 127) * 32; k0 = (rr >> 7) * 32;
  } else {
    const int rr = tile - 7168;
    W = W2; WT = w2T; Nd = 1024; ldT = 4096; rowoff = 0;
    n0 = (rr & 31) * 32; k0 = (rr >> 5) * 32;
  }
  const int tx = threadIdx.x, ty = threadIdx.y;
#pragma unroll
  for (int j = 0; j < 4; ++j)
    t[ty + 8 * j][tx] = W[(size_t)(k0 + ty + 8 * j) * Nd + n0 + tx];
  __syncthreads();
#pragma unroll
  for (int j = 0; j < 4; ++j)
    WT[(size_t)(rowoff + n0 + ty + 8 * j) * ldT + k0 + tx] =
        __float2bfloat16(t[tx][ty + 8 * j]);
}

// ------- bf16 transpose: dst[c][r] = src[r][c], batched over z -------------
__global__ void transpose_bf16(const bf16* __restrict__ src, bf16* __restrict__ dst,
                               int ldsrc, int lddst, long long zs, long long zd) {
  __shared__ bf16 t[32][33];
  const int z = blockIdx.z;
  src += (size_t)z * zs;
  dst += (size_t)z * zd;
  const int tx = threadIdx.x, ty = threadIdx.y;
  const int c0 = blockIdx.x * 32, r0 = blockIdx.y * 32;
#pragma unroll
  for (int j = 0; j < 4; ++j)
    t[ty + 8 * j][tx] = src[(size_t)(r0 + ty + 8 * j) * ldsrc + c0 + tx];
  __syncthreads();
#pragma unroll
  for (int j = 0; j < 4; ++j)
    dst[(size_t)(c0 + ty + 8 * j) * lddst + r0 + tx] = t[tx][ty + 8 * j];
}

extern "C" void kernel_launch(void* const* d_in, const int* in_sizes, int n_in,
                              void* d_out, int out_size, void* d_ws, size_t ws_size,
                              hipStream_t stream) {
  const float* x = (const float*)d_in[0];
  const float* ln1_g = (const float*)d_in[1];
  const float* ln1_b = (const float*)d_in[2];
  const float* Wq = (const float*)d_in[3];
  const float* Wk = (const float*)d_in[4];
  const float* Wv = (const float*)d_in[5];
  const float* ln2_g = (const float*)d_in[6];
  const float* ln2_b = (const float*)d_in[7];
  const float* W1 = (const float*)d_in[8];
  const float* b1 = (const float*)d_in[9];
  const float* W2 = (const float*)d_in[10];
  const float* b2 = (const float*)d_in[11];
  float* out = (float*)d_out;

  constexpr int B = 8, N = 2048, H = 1024, F = 4096;
  constexpr int M = B * N;  // 16384

  const size_t WqkvTB = (size_t)3 * H * H * 2;
  const size_t W1TB = (size_t)H * F * 2;
  const size_t W2TB = (size_t)H * F * 2;
  const size_t yB = (size_t)M * H * 2;
  const size_t vTB = (size_t)M * H * 2;
  const size_t qkvB = (size_t)M * 3 * H * 2;
  const size_t SB1 = (size_t)N * N * 2;   // bf16 scores
  const size_t attB1 = (size_t)N * N * 2;
  const size_t hB = (size_t)M * F * 2;
  const size_t fixedB = WqkvTB + W1TB + W2TB + yB + vTB;

  int g = 8;
  for (; g > 1; g >>= 1) {
    size_t R = qkvB + (size_t)g * (SB1 + attB1);
    if (R < hB) R = hB;
    if (fixedB + R <= ws_size) break;
  }

  char* ws = (char*)d_ws;
  size_t o = 0;
  bf16* wqkvT = (bf16*)(ws + o); o += WqkvTB;
  bf16* w1T = (bf16*)(ws + o);   o += W1TB;
  bf16* w2T = (bf16*)(ws + o);   o += W2TB;
  bf16* y = (bf16*)(ws + o);     o += yB;
  bf16* vT = (bf16*)(ws + o);    o += vTB;
  char* Rb = ws + o;
  bf16* qkv = (bf16*)Rb;
  bf16* S = (bf16*)(Rb + qkvB);
  bf16* att = (bf16*)(Rb + qkvB + (size_t)g * SB1);
  bf16* h = (bf16*)Rb;  // overlays qkv/S/att after attention is done

  const dim3 tb(32, 8);
  transpose_conv_all<<<11264, tb, 0, stream>>>(Wq, Wk, Wv, W1, W2, wqkvT, w1T,
                                               w2T);

  ln_kernel<<<M, 256, 0, stream>>>(x, ln1_g, ln1_b, y);

  gemm_qkv<<<dim3(3 * H / BN, M / BM, 1), 256, 0, stream>>>(
      y, wqkvT, qkv, H, H, H, 3 * H, 0, 0, 0);

  transpose_bf16<<<dim3(H / 32, N / 32, B), tb, 0, stream>>>(
      qkv + 2 * H, vT, 3 * H, N, (long long)N * 3 * H, (long long)H * N);

  for (int b0 = 0; b0 < B; b0 += g) {
    const bf16* qb = qkv + (size_t)b0 * N * 3 * H;
    gemm_qkt<<<dim3(N / BN, N / BM, g), 256, 0, stream>>>(
        qb, qb + H, S, H, 3 * H, 3 * H, N, (long long)N * 3 * H,
        (long long)N * 3 * H, (long long)N * N, 0.03125f);
    softmax_kernel<<<g * N, 256, 0, stream>>>(S, att);
    gemm_pv<<<dim3(H / BN, N / BM, g), 256, 0, stream>>>(
        att, vT + (size_t)b0 * H * N, out + (size_t)b0 * N * H, N, N, N, H,
        (long long)N * N, (long long)H * N, (long long)N * H,
        x + (size_t)b0 * N * H, (long long)N * H, H);
  }

  ln_kernel<<<M, 256, 0, stream>>>(out, ln2_g, ln2_b, y);

  gemm_ffn1<<<dim3(F / BN, M / BM, 1), 256, 0, stream>>>(
      y, w1T, h, H, H, H, F, b1);

  gemm_ffn2<<<dim3(H / BN, M / BM, 1), 256, 0, stream>>>(
      h, w2T, out, F, F, F, H, b2);
}

// Round 12
// 704.552 us; speedup vs baseline: 1.1106x; 1.0026x over previous
//
#include <hip/hip_runtime.h>
#include <hip/hip_bf16.h>

using bf16 = __hip_bfloat16;
typedef __bf16 bf16x8_t __attribute__((ext_vector_type(8)));
typedef float f32x4_t __attribute__((ext_vector_type(4)));

#define BM 128
#define BN 128
#define BK 64

__device__ __forceinline__ void gload_lds16(const void* g, void* l) {
  __builtin_amdgcn_global_load_lds(
      (__attribute__((address_space(1))) void*)g,
      (__attribute__((address_space(3))) void*)l, 16, 0, 0);
}

// GELU via A&S 7.1.25 3-term erf (|err| < 2.5e-5; bf16 output => invisible)
__device__ __forceinline__ float gelu_erf(float t) {
  const float xs = fabsf(t) * 0.70710678118654752f;
  const float u = 1.0f / fmaf(0.47047f, xs, 1.0f);
  float p = fmaf(0.7478556f, u, -0.0958798f);
  p = fmaf(p, u, 0.3480242f);
  const float er = 1.0f - p * u * __expf(-xs * xs);
  const float ers = (t < 0.f) ? -er : er;
  return 0.5f * t * (1.0f + ers);
}

// ---------------- NT GEMM: C[m][n] = sum_k A[m][k] * B[n][k] ----------------
// m97 structure (verified best here): 128x128 tile, BK=64, 4 waves,
// single-buffer LDS (32 KiB), 2 barriers/K-step, multi-block occupancy.
// Slot-XOR swizzle: LDS physical (row, slot) holds global (row, slot^(row&7))
// -> 0 measured bank conflicts with the 16x16 fragment read pattern.
// Block order: XCD-bijective outer, GROUP_M=8 bm-fast super-tiles.
// EPI: 0 = bf16 out; 1 = bf16 out * scale; 2 = f32 out + resid;
//      3 = bf16 out gelu(acc+bias); 4 = f32 out += (in-place) acc + bias
template <int EPI>
__device__ __forceinline__ void gemm_body(
    const bf16* __restrict__ A, const bf16* __restrict__ B,
    void* __restrict__ Cv, int K, int lda, int ldb, int ldc,
    long long sA, long long sB, long long sC, float scale,
    const float* __restrict__ bias,
    const float* __restrict__ resid, long long sR, int ldr) {
  __shared__ __align__(16) bf16 As[BM * BK];
  __shared__ __align__(16) bf16 Bs[BN * BK];
  const int tid = threadIdx.x;
  const int lane = tid & 63, wid = tid >> 6;
  const int z = blockIdx.z;
  A += (size_t)z * sA;
  B += (size_t)z * sB;

  // T1: bijective XCD-aware block swizzle within the z-slice
  const int gx = gridDim.x, gy = gridDim.y;
  const int nwg = gx * gy;
  const int orig = blockIdx.x + gx * blockIdx.y;
  const int q = nwg >> 3, r = nwg & 7;
  const int xcd = orig & 7, loc = orig >> 3;
  const int wg = (xcd < r ? xcd * (q + 1) : r * (q + 1) + (xcd - r) * q) + loc;
  // GROUP_M=8 super-tile: bm-fast within 8-row groups (gy % 8 == 0 here)
  const int m_in = wg & 7;
  const int rest = wg >> 3;
  const int bn = (rest % gx) * BN;
  const int bm = ((rest / gx) * 8 + m_in) * BM;
  const int wr = wid >> 1, wc = wid & 1;

  // staging: 4 chunks/thread/operand; physical chunk ch = (row, slot),
  // global source slot = slot ^ (row&7); LDS dest linear.
  const bf16* ga[4];
  const bf16* gb[4];
  int lofs[4];
#pragma unroll
  for (int i = 0; i < 4; ++i) {
    int cb = i * 256 + wid * 64;  // wave-uniform chunk base
    int ch = cb + lane;
    int rr = ch >> 3, c = ch & 7;
    int cg = c ^ (rr & 7);        // pre-swizzled global slot
    ga[i] = A + (size_t)(bm + rr) * lda + cg * 8;
    gb[i] = B + (size_t)(bn + rr) * ldb + cg * 8;
    lofs[i] = cb * 8;
  }

  f32x4_t acc[4][4];
#pragma unroll
  for (int i = 0; i < 4; ++i)
#pragma unroll
    for (int j = 0; j < 4; ++j) acc[i][j] = (f32x4_t){0.f, 0.f, 0.f, 0.f};

  const int l15 = lane & 15, kg = lane >> 4;
  const int sw = l15 & 7;                 // (row&7) for every row this lane reads
  const int s0 = (kg ^ sw) * 8;           // kk=0 physical slot offset (elems)
  const int s1 = ((4 + kg) ^ sw) * 8;     // kk=1
  const int arow = wr * 64 + l15;
  const int brow = wc * 64 + l15;

  for (int kt = 0; kt < K; kt += BK) {
#pragma unroll
    for (int i = 0; i < 4; ++i) {
      gload_lds16(ga[i] + kt, As + lofs[i]);
      gload_lds16(gb[i] + kt, Bs + lofs[i]);
    }
    __syncthreads();
#pragma unroll
    for (int kk = 0; kk < 2; ++kk) {
      const int so = kk ? s1 : s0;
      bf16x8_t av[4], bv[4];
#pragma unroll
      for (int i = 0; i < 4; ++i)
        av[i] = *(const bf16x8_t*)(As + (arow + i * 16) * BK + so);
#pragma unroll
      for (int j = 0; j < 4; ++j)
        bv[j] = *(const bf16x8_t*)(Bs + (brow + j * 16) * BK + so);
#pragma unroll
      for (int i = 0; i < 4; ++i)
#pragma unroll
        for (int j = 0; j < 4; ++j)
          acc[i][j] = __builtin_amdgcn_mfma_f32_16x16x32_bf16(av[i], bv[j],
                                                              acc[i][j], 0, 0, 0);
    }
    __syncthreads();
  }

  // epilogue (16x16 C/D: col=lane&15, row=(lane>>4)*4+reg)
  const int row0 = bm + wr * 64 + kg * 4;
  const int col0 = bn + wc * 64 + l15;
#pragma unroll
  for (int i = 0; i < 4; ++i) {
#pragma unroll
    for (int j = 0; j < 4; ++j) {
#pragma unroll
      for (int jj = 0; jj < 4; ++jj) {
        const int rr = row0 + i * 16 + jj;
        const int cc = col0 + j * 16;
        const float v = acc[i][j][jj];
        if constexpr (EPI == 0) {
          ((bf16*)Cv)[(size_t)z * sC + (size_t)rr * ldc + cc] = __float2bfloat16(v);
        } else if constexpr (EPI == 1) {
          ((bf16*)Cv)[(size_t)z * sC + (size_t)rr * ldc + cc] =
              __float2bfloat16(v * scale);
        } else if constexpr (EPI == 2) {
          ((float*)Cv)[(size_t)z * sC + (size_t)rr * ldc + cc] =
              v + resid[(size_t)z * sR + (size_t)rr * ldr + cc];
        } else if constexpr (EPI == 3) {
          ((bf16*)Cv)[(size_t)z * sC + (size_t)rr * ldc + cc] =
              __float2bfloat16(gelu_erf(v + bias[cc]));
        } else {
          float* Cf = (float*)Cv + (size_t)z * sC;
          const size_t idx = (size_t)rr * ldc + cc;
          Cf[idx] = Cf[idx] + v + bias[cc];
        }
      }
    }
  }
}

// Named wrappers (rocprof attribution)
__global__ void gemm_qkv(const bf16* A, const bf16* B, void* C, int K, int lda,
                         int ldb, int ldc, long long sA, long long sB,
                         long long sC) {
  gemm_body<0>(A, B, C, K, lda, ldb, ldc, sA, sB, sC, 1.f, nullptr, nullptr, 0, 0);
}
__global__ void gemm_qkt(const bf16* A, const bf16* B, void* C, int K, int lda,
                         int ldb, int ldc, long long sA, long long sB,
                         long long sC, float scale) {
  gemm_body<1>(A, B, C, K, lda, ldb, ldc, sA, sB, sC, scale, nullptr, nullptr, 0, 0);
}
__global__ void gemm_pv(const bf16* A, const bf16* B, void* C, int K, int lda,
                        int ldb, int ldc, long long sA, long long sB,
                        long long sC, const float* resid, long long sR, int ldr) {
  gemm_body<2>(A, B, C, K, lda, ldb, ldc, sA, sB, sC, 1.f, nullptr, resid, sR, ldr);
}
__global__ void gemm_ffn1(const bf16* A, const bf16* B, void* C, int K, int lda,
                          int ldb, int ldc, const float* bias) {
  gemm_body<3>(A, B, C, K, lda, ldb, ldc, 0, 0, 0, 1.f, bias, nullptr, 0, 0);
}
__global__ void gemm_ffn2(const bf16* A, const bf16* B, void* C, int K, int lda,
                          int ldb, int ldc, const float* bias) {
  gemm_body<4>(A, B, C, K, lda, ldb, ldc, 0, 0, 0, 1.f, bias, nullptr, 0, 0);
}

// ---------------- LayerNorm body: fp32 in -> bf16 out, row length 1024 -----
__device__ __forceinline__ void ln_body(const float* __restrict__ X, int row,
                                        const float* __restrict__ gw,
                                        const float* __restrict__ bw,
                                        bf16* __restrict__ Y, float* red) {
  const int tid = threadIdx.x;
  const float4 xv = *(const float4*)(X + (size_t)row * 1024 + tid * 4);
  float s = xv.x + xv.y + xv.z + xv.w;
  float ss = xv.x * xv.x + xv.y * xv.y + xv.z * xv.z + xv.w * xv.w;
#pragma unroll
  for (int o = 32; o; o >>= 1) {
    s += __shfl_xor(s, o);
    ss += __shfl_xor(ss, o);
  }
  if ((tid & 63) == 0) {
    red[tid >> 6] = s;
    red[4 + (tid >> 6)] = ss;
  }
  __syncthreads();
  s = red[0] + red[1] + red[2] + red[3];
  ss = red[4] + red[5] + red[6] + red[7];
  const float mu = s * (1.f / 1024.f);
  const float var = ss * (1.f / 1024.f) - mu * mu;
  const float rs = rsqrtf(var + 1e-5f);
  const float4 gv = *(const float4*)(gw + tid * 4);
  const float4 bv = *(const float4*)(bw + tid * 4);
  union { ushort4 u; bf16 h[4]; } p;
  p.h[0] = __float2bfloat16((xv.x - mu) * rs * gv.x + bv.x);
  p.h[1] = __float2bfloat16((xv.y - mu) * rs * gv.y + bv.y);
  p.h[2] = __float2bfloat16((xv.z - mu) * rs * gv.z + bv.z);
  p.h[3] = __float2bfloat16((xv.w - mu) * rs * gv.w + bv.w);
  *(ushort4*)(Y + (size_t)row * 1024 + tid * 4) = p.u;
}

__global__ void ln_kernel(const float* __restrict__ X, const float* __restrict__ gw,
                          const float* __restrict__ bw, bf16* __restrict__ Y) {
  __shared__ float red[8];
  ln_body(X, blockIdx.x, gw, bw, Y, red);
}

// ---- Fused prologue: 5 weight transposes (tiles 0..11263) + LN1 (rest) ----
// Weight tile t: [0,3072) Wq/Wk/Wv (HxH); [3072,7168) W1 (HxF);
//                [7168,11264) W2 (FxH). LN1 row = blockIdx.x - 11264.
__global__ void prologue_kernel(const float* __restrict__ Wq,
                                const float* __restrict__ Wk,
                                const float* __restrict__ Wv,
                                const float* __restrict__ W1,
                                const float* __restrict__ W2,
                                bf16* __restrict__ wqkvT,
                                bf16* __restrict__ w1T,
                                bf16* __restrict__ w2T,
                                const float* __restrict__ x,
                                const float* __restrict__ ln1_g,
                                const float* __restrict__ ln1_b,
                                bf16* __restrict__ y) {
  __shared__ float t[32][33];
  const int tile = blockIdx.x;
  if (tile >= 11264) {
    ln_body(x, tile - 11264, ln1_g, ln1_b, y, &t[0][0]);
    return;
  }
  const float* W;
  bf16* WT;
  int Nd, ldT, rowoff, n0, k0;
  if (tile < 3072) {
    const int w = tile >> 10, rr = tile & 1023;
    W = (w == 0) ? Wq : (w == 1) ? Wk : Wv;
    WT = wqkvT; Nd = 1024; ldT = 1024; rowoff = w * 1024;
    n0 = (rr & 31) * 32; k0 = (rr >> 5) * 32;
  } else if (tile < 7168) {
    const int rr = tile - 3072;
    W = W1; WT = w1T; Nd = 4096; ldT = 1024; rowoff = 0;
    n0 = (rr & 127) * 32; k0 = (rr >> 7) * 32;
  } else {
    const int rr = tile - 7168;
    W = W2; WT = w2T; Nd = 1024; ldT = 4096; rowoff = 0;
    n0 = (rr & 31) * 32; k0 = (rr >> 5) * 32;
  }
  const int tx = threadIdx.x & 31, ty = threadIdx.x >> 5;
#pragma unroll
  for (int j = 0; j < 4; ++j)
    t[ty + 8 * j][tx] = W[(size_t)(k0 + ty + 8 * j) * Nd + n0 + tx];
  __syncthreads();
#pragma unroll
  for (int j = 0; j < 4; ++j)
    WT[(size_t)(rowoff + n0 + ty + 8 * j) * ldT + k0 + tx] =
        __float2bfloat16(t[tx][ty + 8 * j]);
}

// ---------------- Softmax over rows of 2048 bf16 -> bf16 -------------------
__global__ void softmax_kernel(const bf16* __restrict__ S, bf16* __restrict__ P) {
  const size_t row = blockIdx.x;
  const int tid = threadIdx.x;
  union { uint4 u; unsigned short s[8]; } in;
  in.u = *(const uint4*)(S + row * 2048 + tid * 8);
  float f[8];
#pragma unroll
  for (int j = 0; j < 8; ++j)
    f[j] = __uint_as_float((unsigned)in.s[j] << 16);
  float m = f[0];
#pragma unroll
  for (int j = 1; j < 8; ++j) m = fmaxf(m, f[j]);
  __shared__ float red[4];
#pragma unroll
  for (int o = 32; o; o >>= 1) m = fmaxf(m, __shfl_xor(m, o));
  if ((tid & 63) == 0) red[tid >> 6] = m;
  __syncthreads();
  m = fmaxf(fmaxf(red[0], red[1]), fmaxf(red[2], red[3]));
  float s = 0.f;
#pragma unroll
  for (int j = 0; j < 8; ++j) {
    f[j] = __expf(f[j] - m);
    s += f[j];
  }
#pragma unroll
  for (int o = 32; o; o >>= 1) s += __shfl_xor(s, o);
  __syncthreads();
  if ((tid & 63) == 0) red[tid >> 6] = s;
  __syncthreads();
  s = red[0] + red[1] + red[2] + red[3];
  const float inv = 1.f / s;
  union { uint4 u; bf16 h[8]; } p;
#pragma unroll
  for (int j = 0; j < 8; ++j) p.h[j] = __float2bfloat16(f[j] * inv);
  *(uint4*)(P + row * 2048 + tid * 8) = p.u;
}

// ------- bf16 transpose, 64x64 tiles (128B segments), batched over z -------
__global__ void transpose_bf16(const bf16* __restrict__ src, bf16* __restrict__ dst,
                               int ldsrc, int lddst, long long zs, long long zd) {
  __shared__ bf16 t[64][65];
  const int z = blockIdx.z;
  src += (size_t)z * zs;
  dst += (size_t)z * zd;
  const int tx = threadIdx.x, ty = threadIdx.y;
  const int c0 = blockIdx.x * 64, r0 = blockIdx.y * 64;
#pragma unroll
  for (int j = 0; j < 8; ++j)
    t[ty + 8 * j][tx] = src[(size_t)(r0 + ty + 8 * j) * ldsrc + c0 + tx];
  __syncthreads();
#pragma unroll
  for (int j = 0; j < 8; ++j)
    dst[(size_t)(c0 + ty + 8 * j) * lddst + r0 + tx] = t[tx][ty + 8 * j];
}

extern "C" void kernel_launch(void* const* d_in, const int* in_sizes, int n_in,
                              void* d_out, int out_size, void* d_ws, size_t ws_size,
                              hipStream_t stream) {
  const float* x = (const float*)d_in[0];
  const float* ln1_g = (const float*)d_in[1];
  const float* ln1_b = (const float*)d_in[2];
  const float* Wq = (const float*)d_in[3];
  const float* Wk = (const float*)d_in[4];
  const float* Wv = (const float*)d_in[5];
  const float* ln2_g = (const float*)d_in[6];
  const float* ln2_b = (const float*)d_in[7];
  const float* W1 = (const float*)d_in[8];
  const float* b1 = (const float*)d_in[9];
  const float* W2 = (const float*)d_in[10];
  const float* b2 = (const float*)d_in[11];
  float* out = (float*)d_out;

  constexpr int B = 8, N = 2048, H = 1024, F = 4096;
  constexpr int M = B * N;  // 16384

  const size_t WqkvTB = (size_t)3 * H * H * 2;
  const size_t W1TB = (size_t)H * F * 2;
  const size_t W2TB = (size_t)H * F * 2;
  const size_t yB = (size_t)M * H * 2;
  const size_t vTB = (size_t)M * H * 2;
  const size_t qkvB = (size_t)M * 3 * H * 2;
  const size_t SB1 = (size_t)N * N * 2;   // bf16 scores
  const size_t attB1 = (size_t)N * N * 2;
  const size_t hB = (size_t)M * F * 2;
  const size_t fixedB = WqkvTB + W1TB + W2TB + yB + vTB;

  int g = 8;
  for (; g > 1; g >>= 1) {
    size_t R = qkvB + (size_t)g * (SB1 + attB1);
    if (R < hB) R = hB;
    if (fixedB + R <= ws_size) break;
  }

  char* ws = (char*)d_ws;
  size_t o = 0;
  bf16* wqkvT = (bf16*)(ws + o); o += WqkvTB;
  bf16* w1T = (bf16*)(ws + o);   o += W1TB;
  bf16* w2T = (bf16*)(ws + o);   o += W2TB;
  bf16* y = (bf16*)(ws + o);     o += yB;
  bf16* vT = (bf16*)(ws + o);    o += vTB;
  char* Rb = ws + o;
  bf16* qkv = (bf16*)Rb;
  bf16* S = (bf16*)(Rb + qkvB);
  bf16* att = (bf16*)(Rb + qkvB + (size_t)g * SB1);
  bf16* h = (bf16*)Rb;  // overlays qkv/S/att after attention is done

  // fused weight transpose + LN1 (independent work, one launch)
  prologue_kernel<<<11264 + M, 256, 0, stream>>>(
      Wq, Wk, Wv, W1, W2, wqkvT, w1T, w2T, x, ln1_g, ln1_b, y);

  gemm_qkv<<<dim3(3 * H / BN, M / BM, 1), 256, 0, stream>>>(
      y, wqkvT, qkv, H, H, H, 3 * H, 0, 0, 0);

  transpose_bf16<<<dim3(H / 64, N / 64, B), dim3(64, 8), 0, stream>>>(
      qkv + 2 * H, vT, 3 * H, N, (long long)N * 3 * H, (long long)H * N);

  for (int b0 = 0; b0 < B; b0 += g) {
    const bf16* qb = qkv + (size_t)b0 * N * 3 * H;
    gemm_qkt<<<dim3(N / BN, N / BM, g), 256, 0, stream>>>(
        qb, qb + H, S, H, 3 * H, 3 * H, N, (long long)N * 3 * H,
        (long long)N * 3 * H, (long long)N * N, 0.03125f);
    softmax_kernel<<<g * N, 256, 0, stream>>>(S, att);
    gemm_pv<<<dim3(H / BN, N / BM, g), 256, 0, stream>>>(
        att, vT + (size_t)b0 * H * N, out + (size_t)b0 * N * H, N, N, N, H,
        (long long)N * N, (long long)H * N, (long long)N * H,
        x + (size_t)b0 * N * H, (long long)N * H, H);
  }

  ln_kernel<<<M, 256, 0, stream>>>(out, ln2_g, ln2_b, y);

  gemm_ffn1<<<dim3(F / BN, M / BM, 1), 256, 0, stream>>>(
      y, w1T, h, H, H, H, F, b1);

  gemm_ffn2<<<dim3(H / BN, M / BM, 1), 256, 0, stream>>>(
      h, w2T, out, F, F, F, H, b2);
}